// Round 6
// baseline (1547.525 us; speedup 1.0000x reference)
//
#include <hip/hip_runtime.h>
#include <utility>

// 16-wire statevector sim, batch 128 — ONE dispatch, ONE block per batch.
// Block owns its batch's full 512 KiB state in global workspace; all phase
// handoffs are __syncthreads() (no fences, no cross-block traffic, no L2
// flush — R5 lesson: agent-scope fences cost ~3 GB of L2 writeback traffic).
// Wire w <-> global bit (15-w). Per layer l (r=l+1):
//  P1(l), l>=1: pure-register, bits {15,14,14-l,13-l}: H2(l-1) ctrl-swaps,
//               Rot{0,1,r,r+1}, CNOT(0->r),(1->r+1)
//  P2(l): chunk = fixed bits {15,14}; LDS register sweeps S1{13..10} S2{9..6}
//         S3{5..2} S4{3..0} (+S5 wraps r>=3).
//  L==0: P1 eliminated — embedding x head gates folded into per-chunk
//        register GENERATION (product state, zero global reads).
//  L==5: readout fused into P2 (wrap CNOTs + H2(5) folded into Z signs),
//        no state write-back.

#define NW    16
#define BLK   1024
#define CHUNK 16384

// ---------- static_for ----------
template<class F, int... Is>
__device__ __forceinline__ void static_for_impl(F&& f, std::integer_sequence<int, Is...>) {
    (f(std::integral_constant<int, Is>{}), ...);
}
template<int N, class F>
__device__ __forceinline__ void static_for(F&& f) {
    static_for_impl(f, std::make_integer_sequence<int, N>{});
}

__device__ __forceinline__ int swz(int u) { return u ^ ((u >> 4) & 15); }

// ---------- gate primitives ----------
__device__ __forceinline__ void c2x2(float2& a0, float2& a1,
                                     float2 m00, float2 m01,
                                     float2 m10, float2 m11) {
    float2 r0, r1;
    r0.x = m00.x*a0.x - m00.y*a0.y + m01.x*a1.x - m01.y*a1.y;
    r0.y = m00.x*a0.y + m00.y*a0.x + m01.x*a1.y + m01.y*a1.x;
    r1.x = m10.x*a0.x - m10.y*a0.y + m11.x*a1.x - m11.y*a1.y;
    r1.y = m10.x*a0.y + m10.y*a0.x + m11.x*a1.y + m11.y*a1.x;
    a0 = r0; a1 = r1;
}

__device__ __forceinline__ float2 cmul(float2 a, float2 b) {
    return make_float2(a.x*b.x - a.y*b.y, a.x*b.y + a.y*b.x);
}

template<int Q>
__device__ __forceinline__ void rot_regs(float2 a[16], float2 m00, float2 m01,
                                         float2 m10, float2 m11) {
#pragma unroll
    for (int j = 0; j < 16; ++j)
        if (!((j >> Q) & 1))
            c2x2(a[j], a[j | (1 << Q)], m00, m01, m10, m11);
}

template<int QC, int QT>
__device__ __forceinline__ void cnot_inreg(float2 a[16]) {
#pragma unroll
    for (int j = 0; j < 16; ++j)
        if (((j >> QC) & 1) && !((j >> QT) & 1)) {
            float2 t = a[j]; a[j] = a[j | (1 << QT)]; a[j | (1 << QT)] = t;
        }
}

template<int QT>
__device__ __forceinline__ void cnot_ctrlout(float2 a[16], int ctrl) {
#pragma unroll
    for (int j = 0; j < 16; ++j)
        if (!((j >> QT) & 1)) {
            int j2 = j | (1 << QT);
            float2 x = a[j], y = a[j2];
            a[j].x  = ctrl ? y.x : x.x;  a[j].y  = ctrl ? y.y : x.y;
            a[j2].x = ctrl ? x.x : y.x;  a[j2].y = ctrl ? x.y : y.y;
        }
}

// Rot(phi,theta,omega) = RZ(omega) RY(theta) RZ(phi)
__device__ __forceinline__ void rot_mat(const float* ww, float2 m[4]) {
    float phi = ww[0], th = ww[1], om = ww[2];
    float ct, st;   sincosf(0.5f * th, &st, &ct);
    float cap, sap; sincosf(0.5f * (phi + om), &sap, &cap);
    float cam, sam; sincosf(0.5f * (phi - om), &sam, &cam);
    m[0] = make_float2( cap * ct, -sap * ct);
    m[1] = make_float2(-cam * st, -sam * st);
    m[2] = make_float2( cam * st, -sam * st);
    m[3] = make_float2( cap * ct,  sap * ct);
}

// ---------- pass2 sweep gate driver (validated R4/R5 schedule) ----------
template<int L, int S>
__device__ __forceinline__ int sweep_gates(float2 a[16], const float2 (*gm)[4], int ub) {
    constexpr int r = L + 1;
    constexpr int base = (S == 2) ? 6 : (S == 3) ? 2 : (S == 4) ? 0 : 10;
    int wmask = 0;
    if constexpr (S <= 4) {
        constexpr int plo = (S == 1) ? 10 : (S == 2) ? 6 : (S == 3) ? 2 : 0;
        constexpr int phi = (S == 1) ? 13 : (S == 2) ? 9 : (S == 3) ? 5 : 1;
        static_for<phi - plo + 1>([&](auto K) {
            constexpr int bb = phi - decltype(K)::value;
            if constexpr (bb != 15 - r && bb != 14 - r) {
                constexpr int wire = 15 - bb;
                rot_regs<bb - base>(a, gm[wire][0], gm[wire][1], gm[wire][2], gm[wire][3]);
            }
        });
        static_for<14 - r>([&](auto K) {
            constexpr int i  = 2 + decltype(K)::value;
            constexpr int cb = 15 - i, tb = cb - r;
            if constexpr (tb >= plo && tb <= phi) {
                if constexpr (cb <= base + 3) {
                    cnot_inreg<cb - base, tb - base>(a);
                } else if constexpr (tb - r >= plo) {
                    cnot_ctrlout<tb - base>(a, (ub >> cb) & 1);
                } else {
                    wmask |= ((ub >> cb) & 1) << (tb - base);
                }
            }
        });
    } else {
        static_for<(r >= 3) ? (r - 2) : 0>([&](auto K) {
            constexpr int i  = 18 - r + decltype(K)::value;
            constexpr int cb = 15 - i, tb = 31 - i - r;
            cnot_ctrlout<tb - 10>(a, (ub >> cb) & 1);
        });
    }
    return wmask;
}

// ---------- P1 (l>=1): pure register, bits {15,14,g1,g0} ----------
template<int L>
__device__ void pass1_task(const float2 (*gm)[4], float2* __restrict__ gb, int m) {
    constexpr int r  = L + 1;
    constexpr int g1 = 14 - L, g0 = 13 - L;
    const int T = (m << 10) | (int)threadIdx.x;   // 12-bit task index

    int sb;
    {
        int lo = T & ((1 << g0) - 1);
        int hi = T >> g0;
        sb = lo | (hi << (g1 + 1));               // g1 = g0+1 (adjacent)
    }

    float2 a[16];
#pragma unroll
    for (int j = 0; j < 16; ++j) {
        int s = sb | ((j & 1) << g0) | (((j >> 1) & 1) << g1)
                   | (((j >> 2) & 1) << 14) | (((j >> 3) & 1) << 15);
        a[j] = gb[s];
    }
    // H2(L-1): targets bits 15,14 = reg bits 3,2; ctrl bits L-1,L-2 of sb
    if constexpr (L >= 2) {
        cnot_ctrlout<3>(a, (sb >> (L - 1)) & 1);
        cnot_ctrlout<2>(a, (sb >> (L - 2)) & 1);
    } else {
        cnot_ctrlout<3>(a, sb & 1);    // L==1: only CNOT(w15->w0)
    }

    rot_regs<3>(a, gm[0][0], gm[0][1], gm[0][2], gm[0][3]);         // Rot w0
    rot_regs<2>(a, gm[1][0], gm[1][1], gm[1][2], gm[1][3]);         // Rot w1
    rot_regs<1>(a, gm[r][0], gm[r][1], gm[r][2], gm[r][3]);         // Rot wr
    rot_regs<0>(a, gm[r+1][0], gm[r+1][1], gm[r+1][2], gm[r+1][3]); // Rot wr+1
    cnot_inreg<3, 1>(a);                                            // CNOT(0->r)
    cnot_inreg<2, 0>(a);                                            // CNOT(1->r+1)

#pragma unroll
    for (int j = 0; j < 16; ++j) {
        int s = sb | ((j & 1) << g0) | (((j >> 1) & 1) << g1)
                   | (((j >> 2) & 1) << 14) | (((j >> 3) & 1) << 15);
        gb[s] = a[j];
    }
}

// ---------- P2: LDS-staged register sweeps on one 2^14 chunk ----------
template<int L>
__device__ void pass2_chunk(float2* __restrict__ gb, int c, const float2 (*gm)[4],
                            float2* lds, float* accs,
                            const float* ec, const float* es) {
    constexpr int r = L + 1;
    const int tid = threadIdx.x;
    float2* g = gb + ((size_t)c << 14);
    float2 a[16];
    const int ub1 = tid;

    if constexpr (L == 0) {
        // GENERATE: embedding product state with head gates (Rot w0,w1,w2 +
        // CNOT(0->1),(1->2)) folded: psi3[b0,b1,b2] = v0[b0] v1[b1^b0] v2[b2^b1]
        float2 v[3][2];
#pragma unroll
        for (int wq = 0; wq < 3; ++wq)
#pragma unroll
            for (int bb = 0; bb < 2; ++bb) {
                v[wq][bb].x = gm[wq][2*bb].x * ec[wq] + gm[wq][2*bb+1].x * es[wq];
                v[wq][bb].y = gm[wq][2*bb].y * ec[wq] + gm[wq][2*bb+1].y * es[wq];
            }
        const int b0 = (c >> 1) & 1, b1 = c & 1;
        float2 psiC[2];
#pragma unroll
        for (int b2 = 0; b2 < 2; ++b2)
            psiC[b2] = cmul(cmul(v[0][b0], v[1][b1 ^ b0]), v[2][b2 ^ b1]);
        // wires 6..15 <-> tid bits 9..0 (wire w = 15-k)
        float plo = 1.0f;
#pragma unroll
        for (int k = 0; k < 10; ++k)
            plo *= ((tid >> k) & 1) ? es[15 - k] : ec[15 - k];
#pragma unroll
        for (int j = 0; j < 16; ++j) {   // u bits 13..10 = j; wires 2..5
            float f3 = ((j >> 2) & 1) ? es[3] : ec[3];
            float f4 = ((j >> 1) & 1) ? es[4] : ec[4];
            float f5 = (j & 1)        ? es[5] : ec[5];
            float hb = f3 * f4 * f5 * plo;
            float2 pc = psiC[(j >> 3) & 1];
            a[j] = make_float2(pc.x * hb, pc.y * hb);
        }
    } else {
#pragma unroll
        for (int j = 0; j < 16; ++j) a[j] = g[ub1 | (j << 10)];
    }
    __syncthreads();          // previous chunk's LDS readers done
    {   // S1: group {13..10}
        int wm = sweep_gates<L, 1>(a, gm, ub1) << 10;
#pragma unroll
        for (int j = 0; j < 16; ++j) lds[swz((ub1 | (j << 10)) ^ wm)] = a[j];
    }
    __syncthreads();
    {   // S2: group {9..6}
        const int ub = (tid & 63) | ((tid >> 6) << 10);
#pragma unroll
        for (int j = 0; j < 16; ++j) a[j] = lds[swz(ub | (j << 6))];
        int wm = sweep_gates<L, 2>(a, gm, ub) << 6;
#pragma unroll
        for (int j = 0; j < 16; ++j) lds[swz((ub | (j << 6)) ^ wm)] = a[j];
    }
    __syncthreads();
    {   // S3: group {5..2}
        const int ub = (tid & 3) | ((tid >> 2) << 6);
#pragma unroll
        for (int j = 0; j < 16; ++j) a[j] = lds[swz(ub | (j << 2))];
        int wm = sweep_gates<L, 3>(a, gm, ub) << 2;
#pragma unroll
        for (int j = 0; j < 16; ++j) lds[swz((ub | (j << 2)) ^ wm)] = a[j];
    }
    __syncthreads();
    {   // S4: group {3..0}
        const int ub = tid << 4;
#pragma unroll
        for (int j = 0; j < 16; ++j) a[j] = lds[swz(ub | j)];
        int wm = sweep_gates<L, 4>(a, gm, ub);
#pragma unroll
        for (int j = 0; j < 16; ++j) lds[swz((ub | j) ^ wm)] = a[j];
    }
    __syncthreads();

    if constexpr (L == 5) {
        // Fused readout: r=6 wrap CNOTs (ctrl bits 3..0 -> tgt bits 13..10)
        // and H2(5) (ctrl bits 5,4 -> tgt bits 15,14) folded into signs.
        const int ub = tid;
        float psum = 0.f, z2s = 0.f, z3s = 0.f, z4s = 0.f, z5s = 0.f;
#pragma unroll
        for (int j = 0; j < 16; ++j) {
            float2 v2 = lds[swz(ub | (j << 10))];
            float p = v2.x * v2.x + v2.y * v2.y;
            psum += p;
            z2s += (j & 8) ? -p : p;
            z3s += (j & 4) ? -p : p;
            z4s += (j & 2) ? -p : p;
            z5s += (j & 1) ? -p : p;
        }
        float z[NW];
        z[0] = (((c >> 1) ^ (tid >> 5)) & 1) ? -psum : psum;
        z[1] = (((c) ^ (tid >> 4)) & 1) ? -psum : psum;
        z[2] = ((tid >> 3) & 1) ? -z2s : z2s;
        z[3] = ((tid >> 2) & 1) ? -z3s : z3s;
        z[4] = ((tid >> 1) & 1) ? -z4s : z4s;
        z[5] = (tid & 1) ? -z5s : z5s;
#pragma unroll
        for (int i = 6; i < NW; ++i)
            z[i] = ((tid >> (15 - i)) & 1) ? -psum : psum;
#pragma unroll
        for (int i = 0; i < NW; ++i) {
            float v2 = z[i];
#pragma unroll
            for (int off = 32; off > 0; off >>= 1) v2 += __shfl_down(v2, off, 64);
            if ((tid & 63) == 0) atomicAdd(&accs[i], v2);
        }
    } else if constexpr (r >= 3) {
        // S5: group {13..10}: wrap CNOTs as register ctrl-swaps, coalesced store
        const int ub = tid;
#pragma unroll
        for (int j = 0; j < 16; ++j) a[j] = lds[swz(ub | (j << 10))];
        (void)sweep_gates<L, 5>(a, gm, ub);
#pragma unroll
        for (int j = 0; j < 16; ++j) g[ub | (j << 10)] = a[j];
    } else {
        // plain copy LDS -> global (coalesced float4)
#pragma unroll
        for (int it = 0; it < 8; ++it) {
            int v2 = tid + it * BLK;
            int u = 2 * v2;
            float2 lo = lds[swz(u)];
            float2 hi = lds[swz(u + 1)];
            reinterpret_cast<float4*>(g)[v2] = make_float4(lo.x, lo.y, hi.x, hi.y);
        }
    }
}

// ---------- the mono kernel: one block per batch, one dispatch ----------
__global__ __launch_bounds__(BLK)
void qmono(const float* __restrict__ x, const float* __restrict__ w,
           float* __restrict__ out, float2* __restrict__ psi, int batch) {
    __shared__ float2 lds[CHUNK];
    __shared__ float2 gm[NW][4];
    __shared__ float  ecs[NW], ess[NW], accs[NW];

    const int b = blockIdx.x;
    if (b >= batch) return;
    const int tid = threadIdx.x;
    float2* gb = psi + ((size_t)b << 16);

    if (tid < NW) {
        float s_, c_;
        sincosf(0.5f * x[b * NW + tid], &s_, &c_);
        ecs[tid] = c_; ess[tid] = s_;
        accs[tid] = 0.f;
    }

    static_for<6>([&](auto LC) {
        constexpr int L = decltype(LC)::value;
        __syncthreads();               // prior users of gm done (and ecs ready)
        if (tid < NW) rot_mat(w + (L * NW + tid) * 3, gm[tid]);
        __syncthreads();
        if constexpr (L >= 1) {
            for (int m = 0; m < 4; ++m) pass1_task<L>(gm, gb, m);
            __syncthreads();           // P1 stores visible before P2 loads
        }
        for (int c = 0; c < 4; ++c)
            pass2_chunk<L>(gb, c, gm, lds, accs, ecs, ess);
    });

    __syncthreads();
    if (tid < NW) out[b * NW + tid] = accs[tid];
}

extern "C" void kernel_launch(void* const* d_in, const int* in_sizes, int n_in,
                              void* d_out, int out_size, void* d_ws, size_t ws_size,
                              hipStream_t stream) {
    const float* x = (const float*)d_in[0];   // (B, 16) float32
    const float* w = (const float*)d_in[1];   // (6, 16, 3) float32
    float* out = (float*)d_out;               // (B, 16) float32
    float2* psi = (float2*)d_ws;              // B * 65536 * 8 B = 64 MiB
    int batch = in_sizes[0] / NW;

    qmono<<<batch, BLK, 0, stream>>>(x, w, out, psi, batch);
}

// Round 8
// 573.129 us; speedup vs baseline: 2.7001x; 2.7001x over previous
//
#include <hip/hip_runtime.h>
#include <utility>

// 16-wire statevector sim, batch 128. Multi-dispatch, register-blocked,
// ALL global I/O is float4/lane (R6 lesson: 8B-granule global accesses are
// 2-3.6x amplified at L2/HBM; float4 streams are clean).
// Wire w <-> global bit (15-w). Per layer l (r=l+1):
//  P1(l), l>=1: pure-register, group bits {15,14,14-l,0} (bit0 only for f4):
//               H2(l-1) ctrl-swaps; Rot{0,1,r}; CNOT(0->r). f4 loads/stores.
//  P2(l): chunk fixed bits {15,14}; f4 stage-in -> LDS; register sweeps
//         S1{13..10} S2{9..6} S3{5..2} S4{3..0}; copy-out f4 with wrap-CNOTs
//         folded into LDS read addresses. Rot(r+1) + CNOT(1->r+1) moved here
//         (ctrl = chunk-constant bit14).
//  L==0: P1 folded into P2 generation (embedding product state + head gates).
//  L==5: readout fused into P2 (wrap + H2(5) folded into Z signs), no store.

#define NW    16
#define BLK   1024
#define CHUNK 16384

// ---------- static_for ----------
template<class F, int... Is>
__device__ __forceinline__ void static_for_impl(F&& f, std::integer_sequence<int, Is...>) {
    (f(std::integral_constant<int, Is>{}), ...);
}
template<int N, class F>
__device__ __forceinline__ void static_for(F&& f) {
    static_for_impl(f, std::make_integer_sequence<int, N>{});
}

// bit0-preserving LDS swizzle (keeps float2 pairs adjacent; spreads bank pairs)
__device__ __forceinline__ int swz(int u) { return u ^ (((u >> 4) & 7) << 1); }

// ---------- gate primitives ----------
__device__ __forceinline__ void c2x2(float2& a0, float2& a1,
                                     float2 m00, float2 m01,
                                     float2 m10, float2 m11) {
    float2 r0, r1;
    r0.x = m00.x*a0.x - m00.y*a0.y + m01.x*a1.x - m01.y*a1.y;
    r0.y = m00.x*a0.y + m00.y*a0.x + m01.x*a1.y + m01.y*a1.x;
    r1.x = m10.x*a0.x - m10.y*a0.y + m11.x*a1.x - m11.y*a1.y;
    r1.y = m10.x*a0.y + m10.y*a0.x + m11.x*a1.y + m11.y*a1.x;
    a0 = r0; a1 = r1;
}

__device__ __forceinline__ float2 cmul(float2 a, float2 b) {
    return make_float2(a.x*b.x - a.y*b.y, a.x*b.y + a.y*b.x);
}

template<int Q>
__device__ __forceinline__ void rot_regs(float2 a[16], float2 m00, float2 m01,
                                         float2 m10, float2 m11) {
#pragma unroll
    for (int j = 0; j < 16; ++j)
        if (!((j >> Q) & 1))
            c2x2(a[j], a[j | (1 << Q)], m00, m01, m10, m11);
}

template<int QC, int QT>
__device__ __forceinline__ void cnot_inreg(float2 a[16]) {
#pragma unroll
    for (int j = 0; j < 16; ++j)
        if (((j >> QC) & 1) && !((j >> QT) & 1)) {
            float2 t = a[j]; a[j] = a[j | (1 << QT)]; a[j | (1 << QT)] = t;
        }
}

template<int QT>
__device__ __forceinline__ void cnot_ctrlout(float2 a[16], int ctrl) {
#pragma unroll
    for (int j = 0; j < 16; ++j)
        if (!((j >> QT) & 1)) {
            int j2 = j | (1 << QT);
            float2 x = a[j], y = a[j2];
            a[j].x  = ctrl ? y.x : x.x;  a[j].y  = ctrl ? y.y : x.y;
            a[j2].x = ctrl ? x.x : y.x;  a[j2].y = ctrl ? x.y : y.y;
        }
}

// Rot(phi,theta,omega) = RZ(omega) RY(theta) RZ(phi)
__device__ __forceinline__ void rot_mat(const float* ww, float2 m[4]) {
    float phi = ww[0], th = ww[1], om = ww[2];
    float ct, st;   sincosf(0.5f * th, &st, &ct);
    float cap, sap; sincosf(0.5f * (phi + om), &sap, &cap);
    float cam, sam; sincosf(0.5f * (phi - om), &sam, &cam);
    m[0] = make_float2( cap * ct, -sap * ct);
    m[1] = make_float2(-cam * st, -sam * st);
    m[2] = make_float2( cam * st, -sam * st);
    m[3] = make_float2( cap * ct,  sap * ct);
}

// ---------- P2 sweep driver ----------
// Rots: skip wire r (done in P1); for L==0 also skip wire r+1 (generation).
// Moved-in CNOT(w1->w(r+1)): ctrl = chunk bit14 (c14), applied at i=1 position.
// Ring CNOTs i=2..15-r: in-group / ub-ctrl-swap / LDS-write-addr fold.
template<int L, int S>
__device__ __forceinline__ int sweep_gates(float2 a[16], const float2 (*gm)[4],
                                           int ub, int c14) {
    constexpr int r    = L + 1;
    constexpr int base = (S == 1) ? 10 : (S == 2) ? 6 : (S == 3) ? 2 : 0;
    constexpr int plo  = base;
    constexpr int phi  = (S == 4) ? 1 : base + 3;
    int wmask = 0;
    static_for<phi - plo + 1>([&](auto K) {
        constexpr int bb = phi - decltype(K)::value;
        if constexpr (bb != 15 - r && !(L == 0 && bb == 14 - r)) {
            constexpr int wire = 15 - bb;
            rot_regs<bb - base>(a, gm[wire][0], gm[wire][1], gm[wire][2], gm[wire][3]);
        }
    });
    if constexpr (L >= 1 && (14 - r) >= plo && (14 - r) <= phi)
        cnot_ctrlout<14 - r - base>(a, c14);              // CNOT(w1 -> w(r+1))
    static_for<14 - r>([&](auto K) {
        constexpr int i  = 2 + decltype(K)::value;
        constexpr int cb = 15 - i, tb = cb - r;
        if constexpr (tb >= plo && tb <= phi) {
            if constexpr (cb <= base + 3) {
                cnot_inreg<cb - base, tb - base>(a);      // control in group
            } else if constexpr (tb - r >= plo) {
                cnot_ctrlout<tb - base>(a, (ub >> cb) & 1); // in-sweep successor
            } else {
                wmask |= ((ub >> cb) & 1) << (tb - base); // fold to LDS write
            }
        }
    });
    return wmask;
}

// ---------- P1 (l>=1): pure register, group {15,14,14-L,0}, f4 I/O ----------
template<int L>
__global__ __launch_bounds__(BLK)
void k_p1(const float* __restrict__ w, float2* __restrict__ psi) {
    constexpr int r  = L + 1;
    constexpr int G1 = 14 - L;                // bit of wire r
    const int b = blockIdx.x >> 2, m = blockIdx.x & 3;
    const int T = (m << 10) | (int)threadIdx.x;   // 12-bit
    float2* g = psi + ((size_t)b << 16);

    // deposit T into bits {1..13} \ {G1}
    const int sb = ((T & ((1 << (13 - L)) - 1)) << 1) | ((T >> (13 - L)) << (15 - L));

    float2 m0[4], m1[4], mr[4];
    rot_mat(w + (L * NW + 0) * 3, m0);
    rot_mat(w + (L * NW + 1) * 3, m1);
    rot_mat(w + (L * NW + r) * 3, mr);

    // reg index j: bit0 <-> global bit0, bit1 <-> G1, bit2 <-> 14, bit3 <-> 15
    float2 a[16];
#pragma unroll
    for (int jh = 0; jh < 8; ++jh) {
        int s = sb | ((jh & 1) << G1) | (((jh >> 1) & 1) << 14) | (((jh >> 2) & 1) << 15);
        float4 f = *reinterpret_cast<const float4*>(g + s);
        a[(jh << 1)]     = make_float2(f.x, f.y);
        a[(jh << 1) | 1] = make_float2(f.z, f.w);
    }

    // H2(L-1): targets w0 (reg bit3), w1 (reg bit2); ctrl bits L-1, L-2
    if constexpr (L == 1) {
        cnot_inreg<0, 3>(a);                         // CNOT(w15->w0), ctrl bit0 in-group
    } else if constexpr (L == 2) {
        cnot_ctrlout<3>(a, (sb >> 1) & 1);           // CNOT(w14->w0)
        cnot_inreg<0, 2>(a);                         // CNOT(w15->w1)
    } else {
        cnot_ctrlout<3>(a, (sb >> (L - 1)) & 1);
        cnot_ctrlout<2>(a, (sb >> (L - 2)) & 1);
    }
    rot_regs<3>(a, m0[0], m0[1], m0[2], m0[3]);      // Rot w0
    rot_regs<2>(a, m1[0], m1[1], m1[2], m1[3]);      // Rot w1
    rot_regs<1>(a, mr[0], mr[1], mr[2], mr[3]);      // Rot wr
    cnot_inreg<3, 1>(a);                             // CNOT(w0->wr)

#pragma unroll
    for (int jh = 0; jh < 8; ++jh) {
        int s = sb | ((jh & 1) << G1) | (((jh >> 1) & 1) << 14) | (((jh >> 2) & 1) << 15);
        float2 lo = a[(jh << 1)], hi = a[(jh << 1) | 1];
        *reinterpret_cast<float4*>(g + s) = make_float4(lo.x, lo.y, hi.x, hi.y);
    }
}

// ---------- P2: f4-staged LDS register sweeps, fixed bits {15,14} ----------
template<int L>
__global__ __launch_bounds__(BLK)
void k_p2(const float* __restrict__ x, const float* __restrict__ w,
          float* __restrict__ out, float2* __restrict__ psi) {
    constexpr int r = L + 1;
    __shared__ float2 lds[CHUNK];
    __shared__ float2 gm[NW][4];
    __shared__ float  ecs[NW], ess[NW], accs[NW];
    const int b = blockIdx.x >> 2, c = blockIdx.x & 3;
    const int tid = threadIdx.x;
    const int c14 = c & 1;                    // chunk's wire-1 bit
    float2* g = psi + ((size_t)b << 16) + ((size_t)c << 14);

    if (tid < NW) {
        rot_mat(w + (L * NW + tid) * 3, gm[tid]);
        if (L == 0) {
            float s_, c_; sincosf(0.5f * x[b * NW + tid], &s_, &c_);
            ecs[tid] = c_; ess[tid] = s_;
        }
        if (L == 5) accs[tid] = 0.f;
    }

    if constexpr (L >= 1) {                   // stage-in: coalesced f4 -> LDS
#pragma unroll
        for (int it = 0; it < 8; ++it) {
            int v = tid + it * BLK;
            float4 f = reinterpret_cast<const float4*>(g)[v];
            int u = swz(2 * v);
            lds[u]     = make_float2(f.x, f.y);
            lds[u ^ 1] = make_float2(f.z, f.w);
        }
    }
    __syncthreads();

    float2 a[16];
    {   // S1: group {13..10}
        const int ub = tid;
        if constexpr (L == 0) {
            // generation: embedding product state + Rot{0,1,2} + CNOT(0->1),(1->2)
            float2 v[3][2];
#pragma unroll
            for (int wq = 0; wq < 3; ++wq)
#pragma unroll
                for (int bb = 0; bb < 2; ++bb) {
                    v[wq][bb].x = gm[wq][2*bb].x * ecs[wq] + gm[wq][2*bb+1].x * ess[wq];
                    v[wq][bb].y = gm[wq][2*bb].y * ecs[wq] + gm[wq][2*bb+1].y * ess[wq];
                }
            const int b0 = (c >> 1) & 1, b1 = c & 1;
            float2 psiC[2];
#pragma unroll
            for (int b2 = 0; b2 < 2; ++b2)
                psiC[b2] = cmul(cmul(v[0][b0], v[1][b1 ^ b0]), v[2][b2 ^ b1]);
            float plo = 1.0f;
#pragma unroll
            for (int k = 0; k < 10; ++k)
                plo *= ((tid >> k) & 1) ? ess[15 - k] : ecs[15 - k];
#pragma unroll
            for (int j = 0; j < 16; ++j) {
                float f3 = ((j >> 2) & 1) ? ess[3] : ecs[3];
                float f4 = ((j >> 1) & 1) ? ess[4] : ecs[4];
                float f5 = (j & 1)        ? ess[5] : ecs[5];
                float hb = f3 * f4 * f5 * plo;
                float2 pc = psiC[(j >> 3) & 1];
                a[j] = make_float2(pc.x * hb, pc.y * hb);
            }
        } else {
#pragma unroll
            for (int j = 0; j < 16; ++j) a[j] = lds[swz(ub | (j << 10))];
        }
        int wm = sweep_gates<L, 1>(a, gm, ub, c14) << 10;
#pragma unroll
        for (int j = 0; j < 16; ++j) lds[swz((ub | (j << 10)) ^ wm)] = a[j];
    }
    __syncthreads();
    {   // S2: group {9..6}
        const int ub = (tid & 63) | ((tid >> 6) << 10);
#pragma unroll
        for (int j = 0; j < 16; ++j) a[j] = lds[swz(ub | (j << 6))];
        int wm = sweep_gates<L, 2>(a, gm, ub, c14) << 6;
#pragma unroll
        for (int j = 0; j < 16; ++j) lds[swz((ub | (j << 6)) ^ wm)] = a[j];
    }
    __syncthreads();
    {   // S3: group {5..2}
        const int ub = (tid & 3) | ((tid >> 2) << 6);
#pragma unroll
        for (int j = 0; j < 16; ++j) a[j] = lds[swz(ub | (j << 2))];
        int wm = sweep_gates<L, 3>(a, gm, ub, c14) << 2;
#pragma unroll
        for (int j = 0; j < 16; ++j) lds[swz((ub | (j << 2)) ^ wm)] = a[j];
    }
    __syncthreads();
    {   // S4: group {3..0}
        const int ub = tid << 4;
#pragma unroll
        for (int j = 0; j < 16; ++j) a[j] = lds[swz(ub | j)];
        int wm = sweep_gates<L, 4>(a, gm, ub, c14);
#pragma unroll
        for (int j = 0; j < 16; ++j) lds[swz((ub | j) ^ wm)] = a[j];
    }
    __syncthreads();

    if constexpr (L == 5) {
        // fused readout: wraps (ctrl bits 3..0 -> tgt 13..10) and H2(5)
        // (ctrl bits 5,4 -> tgt 15,14) folded into Z signs
        const int ub = tid;
        float psum = 0.f, z2s = 0.f, z3s = 0.f, z4s = 0.f, z5s = 0.f;
#pragma unroll
        for (int j = 0; j < 16; ++j) {
            float2 v2 = lds[swz(ub | (j << 10))];
            float p = v2.x * v2.x + v2.y * v2.y;
            psum += p;
            z2s += (j & 8) ? -p : p;
            z3s += (j & 4) ? -p : p;
            z4s += (j & 2) ? -p : p;
            z5s += (j & 1) ? -p : p;
        }
        float z[NW];
        z[0] = (((c >> 1) ^ (tid >> 5)) & 1) ? -psum : psum;
        z[1] = (((c) ^ (tid >> 4)) & 1) ? -psum : psum;
        z[2] = ((tid >> 3) & 1) ? -z2s : z2s;
        z[3] = ((tid >> 2) & 1) ? -z3s : z3s;
        z[4] = ((tid >> 1) & 1) ? -z4s : z4s;
        z[5] = (tid & 1) ? -z5s : z5s;
#pragma unroll
        for (int i = 6; i < NW; ++i)
            z[i] = ((tid >> (15 - i)) & 1) ? -psum : psum;
#pragma unroll
        for (int i = 0; i < NW; ++i) {
            float v2 = z[i];
#pragma unroll
            for (int off = 32; off > 0; off >>= 1) v2 += __shfl_down(v2, off, 64);
            if ((tid & 63) == 0) atomicAdd(&accs[i], v2);
        }
        __syncthreads();
        if (tid < NW) atomicAdd(&out[b * NW + tid], accs[tid]);
    } else {
        // copy-out f4; wrap CNOTs (i=18-r..15) folded into LDS READ addresses
#pragma unroll
        for (int it = 0; it < 8; ++it) {
            int v = tid + it * BLK;
            int u = 2 * v;
            int wm0 = 0, wm1 = 0;
            static_for<(r >= 3) ? (r - 2) : 0>([&](auto K) {
                constexpr int k  = decltype(K)::value;
                constexpr int cb = r - 3 - k, tb = 13 - k;
                wm0 |= ((u >> cb) & 1) << tb;
                wm1 |= (((u | 1) >> cb) & 1) << tb;
            });
            float2 lo = lds[swz(u ^ wm0)];
            float2 hi = lds[swz((u | 1) ^ wm1)];
            reinterpret_cast<float4*>(g)[v] = make_float4(lo.x, lo.y, hi.x, hi.y);
        }
    }
}

extern "C" void kernel_launch(void* const* d_in, const int* in_sizes, int n_in,
                              void* d_out, int out_size, void* d_ws, size_t ws_size,
                              hipStream_t stream) {
    const float* x = (const float*)d_in[0];   // (B, 16) float32
    const float* w = (const float*)d_in[1];   // (6, 16, 3) float32
    float* out = (float*)d_out;               // (B, 16) float32
    float2* psi = (float2*)d_ws;              // B * 65536 * 8 B = 64 MiB

    const int batch = in_sizes[0] / NW;
    const int grid  = batch * 4;

    hipMemsetAsync(d_out, 0, (size_t)out_size * sizeof(float), stream);

    k_p2<0><<<grid, BLK, 0, stream>>>(x, w, out, psi);
    k_p1<1><<<grid, BLK, 0, stream>>>(w, psi);
    k_p2<1><<<grid, BLK, 0, stream>>>(x, w, out, psi);
    k_p1<2><<<grid, BLK, 0, stream>>>(w, psi);
    k_p2<2><<<grid, BLK, 0, stream>>>(x, w, out, psi);
    k_p1<3><<<grid, BLK, 0, stream>>>(w, psi);
    k_p2<3><<<grid, BLK, 0, stream>>>(x, w, out, psi);
    k_p1<4><<<grid, BLK, 0, stream>>>(w, psi);
    k_p2<4><<<grid, BLK, 0, stream>>>(x, w, out, psi);
    k_p1<5><<<grid, BLK, 0, stream>>>(w, psi);
    k_p2<5><<<grid, BLK, 0, stream>>>(x, w, out, psi);
}

// Round 9
// 493.599 us; speedup vs baseline: 3.1352x; 1.1611x over previous
//
#include <hip/hip_runtime.h>
#include <utility>

// 16-wire statevector sim, batch B. All global I/O float4 or wave-contiguous.
// Chunks fix bits {15,14,13} (wires 0,1,2) -> 64KB LDS, 2 blocks/CU overlap.
// Wire w <-> global bit (15-w). Per layer l (r=l+1):
//  P1(l), l>=1: pure-register, group {15,14,13,0}: H3(l-1) wraps (tgt w0,w1,w2),
//               Rot{0,1,2}; for l==1 also CNOT(0->2). f4 I/O.
//  P2(l): chunk c = bits {15,14,13}; register sweeps S1{12..9} S2{8..5}
//         S3{4..1} S4{0} over LDS (padded idx u+(u>>4)); Rot(w3..w15);
//         ring CNOTs i=0..15-r (i=0,1,2 ctrls are chunk-constant c bits);
//         wraps tgt w3..w5 folded into copy-out LDS-read addrs.
//  L==0: embedding+head gates generated directly in S1 registers.
//  L==5: readout from S4 registers (all trailing CNOTs folded into Z signs).

#define NW    16
#define P1BLK 1024
#define P2BLK 512
#define CHUNK 8192              // 2^13 amps per chunk
#define LDSN  (CHUNK + CHUNK / 16)

// ---------- static_for ----------
template<class F, int... Is>
__device__ __forceinline__ void static_for_impl(F&& f, std::integer_sequence<int, Is...>) {
    (f(std::integral_constant<int, Is>{}), ...);
}
template<int N, class F>
__device__ __forceinline__ void static_for(F&& f) {
    static_for_impl(f, std::make_integer_sequence<int, N>{});
}

__device__ __forceinline__ int pidx(int u) { return u + (u >> 4); }  // padded LDS idx

// ---------- gate primitives ----------
__device__ __forceinline__ void c2x2(float2& a0, float2& a1,
                                     float2 m00, float2 m01,
                                     float2 m10, float2 m11) {
    float2 r0, r1;
    r0.x = m00.x*a0.x - m00.y*a0.y + m01.x*a1.x - m01.y*a1.y;
    r0.y = m00.x*a0.y + m00.y*a0.x + m01.x*a1.y + m01.y*a1.x;
    r1.x = m10.x*a0.x - m10.y*a0.y + m11.x*a1.x - m11.y*a1.y;
    r1.y = m10.x*a0.y + m10.y*a0.x + m11.x*a1.y + m11.y*a1.x;
    a0 = r0; a1 = r1;
}

__device__ __forceinline__ float2 cmul(float2 a, float2 b) {
    return make_float2(a.x*b.x - a.y*b.y, a.x*b.y + a.y*b.x);
}

template<int Q>
__device__ __forceinline__ void rot_regs(float2 a[16], float2 m00, float2 m01,
                                         float2 m10, float2 m11) {
#pragma unroll
    for (int j = 0; j < 16; ++j)
        if (!((j >> Q) & 1))
            c2x2(a[j], a[j | (1 << Q)], m00, m01, m10, m11);
}

template<int QC, int QT>
__device__ __forceinline__ void cnot_inreg(float2 a[16]) {
#pragma unroll
    for (int j = 0; j < 16; ++j)
        if (((j >> QC) & 1) && !((j >> QT) & 1)) {
            float2 t = a[j]; a[j] = a[j | (1 << QT)]; a[j | (1 << QT)] = t;
        }
}

template<int QT>
__device__ __forceinline__ void cnot_ctrlout(float2 a[16], int ctrl) {
#pragma unroll
    for (int j = 0; j < 16; ++j)
        if (!((j >> QT) & 1)) {
            int j2 = j | (1 << QT);
            float2 x = a[j], y = a[j2];
            a[j].x  = ctrl ? y.x : x.x;  a[j].y  = ctrl ? y.y : x.y;
            a[j2].x = ctrl ? x.x : y.x;  a[j2].y = ctrl ? x.y : y.y;
        }
}

// Rot(phi,theta,omega) = RZ(omega) RY(theta) RZ(phi)
__device__ __forceinline__ void rot_mat(const float* ww, float2 m[4]) {
    float phi = ww[0], th = ww[1], om = ww[2];
    float ct, st;   sincosf(0.5f * th, &st, &ct);
    float cap, sap; sincosf(0.5f * (phi + om), &sap, &cap);
    float cam, sam; sincosf(0.5f * (phi - om), &sam, &cam);
    m[0] = make_float2( cap * ct, -sap * ct);
    m[1] = make_float2(-cam * st, -sam * st);
    m[2] = make_float2( cam * st, -sam * st);
    m[3] = make_float2( cap * ct,  sap * ct);
}

// ---------- P2 sweep driver ----------
constexpr int swof(int tb) { return tb >= 9 ? 1 : tb >= 5 ? 2 : tb >= 1 ? 3 : 4; }

// group: S1{12..9} S2{8..5} S3{4..1} S4{3..0}. Rots: S1 b12..9, S2 8..5,
// S3 4..1, S4 bit0. CNOTs assigned to sweep of target; ctrl from group (inreg),
// c bits (cb>=13), or ub skeleton; defer to LDS-write wmask when chain
// successor is not in this sweep.
template<int L, int S>
__device__ __forceinline__ int sweep_gates(float2 a[16], const float2 (*gm)[4],
                                           int ub, int c) {
    constexpr int r    = L + 1;
    constexpr int base = (S == 1) ? 9 : (S == 2) ? 5 : (S == 3) ? 1 : 0;
    constexpr int rlo  = base;
    constexpr int rhi  = (S == 1) ? 12 : (S == 2) ? 8 : (S == 3) ? 4 : 0;
    static_for<rhi - rlo + 1>([&](auto K) {
        constexpr int bb   = rhi - decltype(K)::value;
        constexpr int wire = 15 - bb;
        rot_regs<bb - base>(a, gm[wire][0], gm[wire][1], gm[wire][2], gm[wire][3]);
    });
    int wmask = 0;
    static_for<16>([&](auto I) {
        constexpr int i = decltype(I)::value;
        if constexpr (i + r < 16) {                       // non-wrap ring CNOT
            constexpr int cb = 15 - i, tb = cb - r;
            constexpr bool skip = (L == 0 && i <= 1) || (L == 1 && i == 0);
            if constexpr (!skip && swof(tb) == S) {
                if constexpr (cb >= base && cb <= base + 3) {
                    cnot_inreg<cb - base, tb - base>(a);
                } else {
                    int ctrl = (cb >= 13) ? ((c >> (cb - 13)) & 1)
                                          : ((ub >> cb) & 1);
                    constexpr int ts = tb - r;            // chain successor tgt
                    if constexpr (ts >= 0 && swof(ts) == S)
                        cnot_ctrlout<tb - base>(a, ctrl);
                    else
                        wmask |= ctrl << (tb - base);
                }
            }
        }
    });
    return wmask;
}

// ---------- P1 (l>=1): pure register, group {15,14,13,0}, f4 I/O ----------
template<int LL>
__global__ __launch_bounds__(P1BLK)
void k_p1(const float* __restrict__ w, float2* __restrict__ psi) {
    const int b = blockIdx.x >> 2;
    const int T = ((blockIdx.x & 3) << 10) | (int)threadIdx.x;   // 12-bit
    float2* g = psi + ((size_t)b << 16);
    const int sb = T << 1;                                       // bits 12..1

    float2 m0[4], m1[4], m2[4];
    rot_mat(w + (LL * NW + 0) * 3, m0);
    rot_mat(w + (LL * NW + 1) * 3, m1);
    rot_mat(w + (LL * NW + 2) * 3, m2);

    // reg j: b0<->bit0(w15), b1<->bit13(w2), b2<->bit14(w1), b3<->bit15(w0)
    float2 a[16];
#pragma unroll
    for (int jh = 0; jh < 8; ++jh) {
        int s = sb | ((jh & 1) << 13) | (((jh >> 1) & 1) << 14) | (((jh >> 2) & 1) << 15);
        float4 f = *reinterpret_cast<const float4*>(g + s);
        a[(jh << 1)]     = make_float2(f.x, f.y);
        a[(jh << 1) | 1] = make_float2(f.z, f.w);
    }

    // H3(LL-1): wraps of layer LL-1 targeting w0,w1,w2 (ctrl bit = (LL-1)-j)
    if constexpr (LL == 1) {
        cnot_inreg<0, 3>(a);
    } else if constexpr (LL == 2) {
        cnot_ctrlout<3>(a, (sb >> 1) & 1);
        cnot_inreg<0, 2>(a);
    } else if constexpr (LL == 3) {
        cnot_ctrlout<3>(a, (sb >> 2) & 1);
        cnot_ctrlout<2>(a, (sb >> 1) & 1);
        cnot_inreg<0, 1>(a);
    } else if constexpr (LL == 4) {
        cnot_ctrlout<3>(a, (sb >> 3) & 1);
        cnot_ctrlout<2>(a, (sb >> 2) & 1);
        cnot_ctrlout<1>(a, (sb >> 1) & 1);
    } else {
        cnot_ctrlout<3>(a, (sb >> 4) & 1);
        cnot_ctrlout<2>(a, (sb >> 3) & 1);
        cnot_ctrlout<1>(a, (sb >> 2) & 1);
    }

    rot_regs<3>(a, m0[0], m0[1], m0[2], m0[3]);   // Rot w0
    rot_regs<2>(a, m1[0], m1[1], m1[2], m1[3]);   // Rot w1
    rot_regs<1>(a, m2[0], m2[1], m2[2], m2[3]);   // Rot w2
    if constexpr (LL == 1) cnot_inreg<3, 1>(a);   // CNOT(w0->w2), layer 1 i=0

#pragma unroll
    for (int jh = 0; jh < 8; ++jh) {
        int s = sb | ((jh & 1) << 13) | (((jh >> 1) & 1) << 14) | (((jh >> 2) & 1) << 15);
        float2 lo = a[(jh << 1)], hi = a[(jh << 1) | 1];
        *reinterpret_cast<float4*>(g + s) = make_float4(lo.x, lo.y, hi.x, hi.y);
    }
}

// ---------- P2: LDS register sweeps, chunk fixed bits {15,14,13} ----------
template<int L>
__global__ __launch_bounds__(P2BLK, 4)
void k_p2(const float* __restrict__ x, const float* __restrict__ w,
          float* __restrict__ out, float2* __restrict__ psi) {
    __shared__ float2 lds[LDSN];
    __shared__ float2 gm[NW][4];
    __shared__ float  ecs[NW], ess[NW], accs[NW];
    const int b = blockIdx.x >> 3, c = blockIdx.x & 7;
    const int tid = threadIdx.x;
    float2* g = psi + ((size_t)b << 16) + ((size_t)c << 13);

    if (tid < NW) {
        rot_mat(w + (L * NW + tid) * 3, gm[tid]);
        if (L == 0) {
            float s_, c_; sincosf(0.5f * x[b * NW + tid], &s_, &c_);
            ecs[tid] = c_; ess[tid] = s_;
        }
        if (L == 5) accs[tid] = 0.f;
    }
    __syncthreads();

    float2 a[16];
    {   // S1: group {12..9}; stage-in direct to regs (or generate for L==0)
        const int ub = tid;
        if constexpr (L == 0) {
            // embedding product state + Rot{0,1,2} + CNOT(0->1),(1->2):
            // wires 0,1,2 are chunk bits c2,c1,c0
            float2 v[3][2];
#pragma unroll
            for (int wq = 0; wq < 3; ++wq)
#pragma unroll
                for (int bb = 0; bb < 2; ++bb) {
                    v[wq][bb].x = gm[wq][2*bb].x * ecs[wq] + gm[wq][2*bb+1].x * ess[wq];
                    v[wq][bb].y = gm[wq][2*bb].y * ecs[wq] + gm[wq][2*bb+1].y * ess[wq];
                }
            const int c2 = (c >> 2) & 1, c1 = (c >> 1) & 1, c0 = c & 1;
            float2 cs = cmul(cmul(v[0][c2], v[1][c1 ^ c2]), v[2][c0 ^ c1]);
            float plo = 1.0f;
#pragma unroll
            for (int k = 0; k < 9; ++k)          // u bits 8..0 <-> wires 15..7
                plo *= ((tid >> k) & 1) ? ess[15 - k] : ecs[15 - k];
#pragma unroll
            for (int j = 0; j < 16; ++j) {       // j bits 3..0 <-> wires 3..6
                float f = plo * ((j & 8) ? ess[3] : ecs[3])
                              * ((j & 4) ? ess[4] : ecs[4])
                              * ((j & 2) ? ess[5] : ecs[5])
                              * ((j & 1) ? ess[6] : ecs[6]);
                a[j] = make_float2(cs.x * f, cs.y * f);
            }
        } else {
#pragma unroll
            for (int j = 0; j < 16; ++j)         // wave-contiguous 8B loads
                a[j] = g[tid | (j << 9)];
        }
        int wm = sweep_gates<L, 1>(a, gm, ub, c) << 9;
#pragma unroll
        for (int j = 0; j < 16; ++j) lds[pidx((tid | (j << 9)) ^ wm)] = a[j];
    }
    __syncthreads();
    {   // S2: group {8..5}
        const int ub = (tid & 31) | ((tid >> 5) << 9);
#pragma unroll
        for (int j = 0; j < 16; ++j) a[j] = lds[pidx(ub | (j << 5))];
        int wm = sweep_gates<L, 2>(a, gm, ub, c) << 5;
#pragma unroll
        for (int j = 0; j < 16; ++j) lds[pidx((ub | (j << 5)) ^ wm)] = a[j];
    }
    __syncthreads();
    {   // S3: group {4..1}
        const int ub = (tid & 1) | ((tid >> 1) << 5);
#pragma unroll
        for (int j = 0; j < 16; ++j) a[j] = lds[pidx(ub | (j << 1))];
        int wm = sweep_gates<L, 3>(a, gm, ub, c) << 1;
#pragma unroll
        for (int j = 0; j < 16; ++j) lds[pidx((ub | (j << 1)) ^ wm)] = a[j];
    }
    __syncthreads();
    {   // S4: group {3..0}
        const int ub = tid << 4;
#pragma unroll
        for (int j = 0; j < 16; ++j) a[j] = lds[pidx(ub | j)];
        int wm = sweep_gates<L, 4>(a, gm, ub, c);

        if constexpr (L == 5) {
            // readout from regs; trailing CNOTs folded into Z signs:
            // H3(5): w0^u5 w1^u4 w2^u3; wraps: w3^u2 w4^u1 w5^u0; wm relabels j
            float psum = 0.f, sb3 = 0.f, sb2 = 0.f, sb1 = 0.f, sb0 = 0.f;
#pragma unroll
            for (int j = 0; j < 16; ++j) {
                int jj = j ^ wm;
                float2 v2 = a[j];
                float p = v2.x * v2.x + v2.y * v2.y;
                psum += p;
                sb3 += (jj & 8) ? -p : p;
                sb2 += (jj & 4) ? -p : p;
                sb1 += (jj & 2) ? -p : p;
                sb0 += (jj & 1) ? -p : p;
            }
            const int c2 = (c >> 2) & 1, c1 = (c >> 1) & 1, c0 = c & 1;
            float z[NW];
            z[0]  = ((c2 ^ (tid >> 1)) & 1) ? -psum : psum;
            z[1]  = ((c1 ^ tid) & 1)        ? -psum : psum;
            z[2]  = c0 ? -sb3 : sb3;
            z[3]  = ((tid >> 8) & 1) ? -sb2 : sb2;
            z[4]  = ((tid >> 7) & 1) ? -sb1 : sb1;
            z[5]  = ((tid >> 6) & 1) ? -sb0 : sb0;
#pragma unroll
            for (int i = 6; i < 12; ++i)
                z[i] = ((tid >> (11 - i)) & 1) ? -psum : psum;
            z[12] = sb3; z[13] = sb2; z[14] = sb1; z[15] = sb0;
#pragma unroll
            for (int i = 0; i < NW; ++i) {
                float v2 = z[i];
#pragma unroll
                for (int off = 32; off > 0; off >>= 1)
                    v2 += __shfl_down(v2, off, 64);
                if ((tid & 63) == 0) atomicAdd(&accs[i], v2);
            }
            __syncthreads();
            if (tid < NW) atomicAdd(&out[b * NW + tid], accs[tid]);
        } else {
#pragma unroll
            for (int j = 0; j < 16; ++j) lds[pidx((ub | j) ^ wm)] = a[j];
            __syncthreads();
            // copy-out f4; wraps tgt w3..w5 folded into LDS read addrs
#pragma unroll
            for (int it = 0; it < CHUNK / 2 / P2BLK; ++it) {
                int v = tid + it * P2BLK;
                int u = 2 * v;
                int wm0 = 0, wm1 = 0;
                static_for<(L >= 3) ? (L - 2) : 0>([&](auto K) {
                    constexpr int k  = decltype(K)::value;
                    constexpr int cbb = L - 3 - k, tbb = 12 - k;
                    wm0 |= ((u >> cbb) & 1) << tbb;
                    wm1 |= (((u | 1) >> cbb) & 1) << tbb;
                });
                float2 lo = lds[pidx(u ^ wm0)];
                float2 hi = lds[pidx((u | 1) ^ wm1)];
                reinterpret_cast<float4*>(g)[v] = make_float4(lo.x, lo.y, hi.x, hi.y);
            }
        }
    }
}

extern "C" void kernel_launch(void* const* d_in, const int* in_sizes, int n_in,
                              void* d_out, int out_size, void* d_ws, size_t ws_size,
                              hipStream_t stream) {
    const float* x = (const float*)d_in[0];   // (B, 16) float32
    const float* w = (const float*)d_in[1];   // (6, 16, 3) float32
    float* out = (float*)d_out;               // (B, 16) float32
    float2* psi = (float2*)d_ws;              // B * 65536 * 8 B

    const int batch = in_sizes[0] / NW;
    const int g1 = batch * 4;                 // P1 grid
    const int g2 = batch * 8;                 // P2 grid

    hipMemsetAsync(d_out, 0, (size_t)out_size * sizeof(float), stream);

    k_p2<0><<<g2, P2BLK, 0, stream>>>(x, w, out, psi);
    k_p1<1><<<g1, P1BLK, 0, stream>>>(w, psi);
    k_p2<1><<<g2, P2BLK, 0, stream>>>(x, w, out, psi);
    k_p1<2><<<g1, P1BLK, 0, stream>>>(w, psi);
    k_p2<2><<<g2, P2BLK, 0, stream>>>(x, w, out, psi);
    k_p1<3><<<g1, P1BLK, 0, stream>>>(w, psi);
    k_p2<3><<<g2, P2BLK, 0, stream>>>(x, w, out, psi);
    k_p1<4><<<g1, P1BLK, 0, stream>>>(w, psi);
    k_p2<4><<<g2, P2BLK, 0, stream>>>(x, w, out, psi);
    k_p1<5><<<g1, P1BLK, 0, stream>>>(w, psi);
    k_p2<5><<<g2, P2BLK, 0, stream>>>(x, w, out, psi);
}